// Round 5
// baseline (159.609 us; speedup 1.0000x reference)
//
#include <hip/hip_runtime.h>

// Tensor-train forward, B=4096 N=8 F=64 D=64 C=10.
// R5 = R4 + explicit register double-buffered batch-8 A-prefetch in the mid
// loop (R4 showed MfmaUtil=VALUBusy=7%, VGPR=48: latency-bound, compiler kept
// ~2 loads in flight). 32 loads in flight/wave forces the MLP needed to reach
// the per-CU L2-share wall. Grid stays 256x512 (per-CU A-traffic = 3.15 MB
// invariant; more blocks/CU would multiply it).

typedef _Float16 half8 __attribute__((ext_vector_type(8)));
typedef _Float16 half4 __attribute__((ext_vector_type(4)));
typedef _Float16 half2v __attribute__((ext_vector_type(2)));
typedef float f32x4 __attribute__((ext_vector_type(4)));

#define LAST_OFF   0
#define MID_OFF    4096
#define MID_SZ     262144
#define FIRST_OFF  1576960
#define N_FRAGS    3208

// ---------- prologue: fp32 cores -> f16, MFMA-A-fragment swizzled ----------
// A-frag (16x16x32 f16): lane holds A[m=lane&15][k=(lane>>4)*8 + j], j=0..7.
__global__ __launch_bounds__(256) void tt_swz(
    const float* __restrict__ cf,   // core_first (10,64,64)  [c][p][r]
    const float* __restrict__ cm,   // cores_mid  (6,64,64,64)[ci][l][p][r]
    const float* __restrict__ cl,   // core_last  (64,64)     [l][p]
    _Float16* __restrict__ ws)
{
  int gid = blockIdx.x * 256 + threadIdx.x;
  if (gid >= N_FRAGS * 64) return;
  int lane = gid & 63, frag = gid >> 6;
  int quad = lane >> 4, m16 = lane & 15;
  half8 hv;
  _Float16* dst;
  if (frag < 8) {                       // core_last: rows l (4 tiles), k = p
    int t = frag >> 1, kt = frag & 1;
    int l = t * 16 + m16;
    const float* s = cl + l * 64 + kt * 32 + quad * 8;
#pragma unroll
    for (int j = 0; j < 8; ++j) hv[j] = (_Float16)s[j];
    dst = ws + LAST_OFF + (size_t)((t * 2 + kt) * 64 + lane) * 8;
  } else if (frag < 8 + 3072) {         // mid cores: rows (p,l), k = r
    int f2 = frag - 8;
    int ci = f2 >> 9, rem = f2 & 511;
    int t = rem >> 1, kt = rem & 1;
    int l = (t & 3) * 16 + m16, p = t >> 2;
    const float* s = cm + (((size_t)ci * 64 + l) * 64 + p) * 64 + kt * 32 + quad * 8;
#pragma unroll
    for (int j = 0; j < 8; ++j) hv[j] = (_Float16)s[j];
    dst = ws + MID_OFF + (size_t)ci * MID_SZ + (size_t)(rem * 64 + lane) * 8;
  } else {                              // core_first: rows c (pad 16), k = r
    int f2 = frag - 3080;
    int t = f2 >> 1, kt = f2 & 1;
    int c = m16, p = t;
    if (c < 10) {
      const float* s = cf + ((size_t)(c * 64 + p)) * 64 + kt * 32 + quad * 8;
#pragma unroll
      for (int j = 0; j < 8; ++j) hv[j] = (_Float16)s[j];
    } else {
#pragma unroll
      for (int j = 0; j < 8; ++j) hv[j] = (_Float16)0.f;
    }
    dst = ws + FIRST_OFF + (size_t)((t * 2 + kt) * 64 + lane) * 8;
  }
  *(half8*)dst = hv;
}

#define LD8(DST, JB) { _Pragma("unroll") for (int i_ = 0; i_ < 8; ++i_) { \
    const _Float16* fp_ = wl + (size_t)((JB) + i_) * 8192; \
    DST[2*i_]   = *(const half8*)fp_; \
    DST[2*i_+1] = *(const half8*)(fp_ + 512); } }

#define CP8(SRC, XR) { _Pragma("unroll") for (int i_ = 0; i_ < 8; ++i_) { \
    f32x4 dd_ = {0.f, 0.f, 0.f, 0.f}; \
    dd_ = __builtin_amdgcn_mfma_f32_16x16x32_f16(SRC[2*i_],   b0, dd_, 0, 0, 0); \
    dd_ = __builtin_amdgcn_mfma_f32_16x16x32_f16(SRC[2*i_+1], b1, dd_, 0, 0, 0); \
    float xv_ = (float)XR[i_]; \
    a0 += xv_ * dd_[0]; a1 += xv_ * dd_[1]; \
    a2 += xv_ * dd_[2]; a3 += xv_ * dd_[3]; } }

// ------------------- main chain: 256 blocks x 512 threads ------------------
__global__ __launch_bounds__(512, 2) void tt_main(
    const float* __restrict__ x,        // (4096, 8, 64)
    const _Float16* __restrict__ ws,
    float* __restrict__ out)            // (4096, 10)
{
  // XT[s][n*80 + par*40 + (p>>1)] : parity-split transposed x, f16.
  __shared__ __align__(16) _Float16 XT[16][648];
  __shared__ __align__(16) _Float16 Vt[2][16][72];   // v partials [part][s][l]
  __shared__ __align__(16) float Red[8][16][16];     // final per-wave partials
  const int tid = threadIdx.x;
  const int w = tid >> 6, lane = tid & 63;
  const int quad = lane >> 4, sl = lane & 15;
  const int blk = blockIdx.x;

  // ---- stage x (16 samples x 512 floats -> f16, parity-split transpose) ----
  {
    const float* xb = x + (size_t)blk * 16 * 512;
    int s = tid >> 5, q = tid & 31;
#pragma unroll
    for (int k = 0; k < 4; ++k) {
      int f4 = q + 32 * k;                       // float4 index 0..127
      float4 v = *(const float4*)(xb + (size_t)s * 512 + (size_t)f4 * 4);
      int n = f4 >> 4, i2 = (f4 & 15) * 2;
      _Float16* row = &XT[s][n * 80];
      half2v e0; e0[0] = (_Float16)v.x; e0[1] = (_Float16)v.z;
      half2v e1; e1[0] = (_Float16)v.y; e1[1] = (_Float16)v.w;
      *(half2v*)&row[i2] = e0;                   // even p
      *(half2v*)&row[40 + i2] = e1;              // odd p
    }
  }
  __syncthreads();

  // ---- GEMM1 (core_last): 8 wave-tasks = (kt = w>>2, tt = w&3) ----
  {
    int tt = w & 3, kt = w >> 2;
    const _Float16* r7 = &XT[sl][7 * 80];
    half4 e0 = *(const half4*)&r7[kt * 16 + quad * 4];        // even p
    half4 e1 = *(const half4*)&r7[40 + kt * 16 + quad * 4];   // odd p
    half8 b;
#pragma unroll
    for (int i = 0; i < 4; ++i) { b[2 * i] = e0[i]; b[2 * i + 1] = e1[i]; }
    half8 a = *(const half8*)(ws + LAST_OFF + (size_t)((tt * 2 + kt) * 64 + lane) * 8);
    f32x4 d = {0.f, 0.f, 0.f, 0.f};
    d = __builtin_amdgcn_mfma_f32_16x16x32_f16(a, b, d, 0, 0, 0);
    half4 hv;
#pragma unroll
    for (int r = 0; r < 4; ++r) hv[r] = (_Float16)d[r];
    *(half4*)&Vt[kt][sl][tt * 16 + quad * 4] = hv;
  }
  __syncthreads();

  const int pr = w >> 2;                 // my p-parity (also Vt partial id)
  const int lch = (w & 3) * 16;
  // ---- 6 middle steps (cores_mid[5] .. cores_mid[0]) ----
  for (int step = 0; step < 6; ++step) {
    int ci = 5 - step;
    // B-frags: v[r][s] = sum of the two p-parity partials
    half8 b0 = *(const half8*)&Vt[0][sl][quad * 8];
    half8 b0b = *(const half8*)&Vt[1][sl][quad * 8];
    half8 b1 = *(const half8*)&Vt[0][sl][32 + quad * 8];
    half8 b1b = *(const half8*)&Vt[1][sl][32 + quad * 8];
    b0 = b0 + b0b; b1 = b1 + b1b;
    // x preload for this step: 32 halves of parity pr (p = 2j + pr, j=0..31)
    const _Float16* xrow = &XT[sl][(ci + 1) * 80 + pr * 40];
    half8 xr0 = *(const half8*)&xrow[0];
    half8 xr1 = *(const half8*)&xrow[8];
    half8 xr2 = *(const half8*)&xrow[16];
    half8 xr3 = *(const half8*)&xrow[24];
    __syncthreads();                     // Vt reads done before overwrite
    const _Float16* wl = ws + MID_OFF + (size_t)ci * MID_SZ
                       + (size_t)w * 1024 + (size_t)lane * 8;
    float a0 = 0.f, a1 = 0.f, a2 = 0.f, a3 = 0.f;
    half8 Aa[16], Ab[16];
    LD8(Aa, 0);
    LD8(Ab, 8);
    CP8(Aa, xr0);
    LD8(Aa, 16);
    CP8(Ab, xr1);
    LD8(Ab, 24);
    CP8(Aa, xr2);
    CP8(Ab, xr3);
    half4 hv;
    hv[0] = (_Float16)a0; hv[1] = (_Float16)a1;
    hv[2] = (_Float16)a2; hv[3] = (_Float16)a3;
    *(half4*)&Vt[pr][sl][lch + quad * 4] = hv;
    __syncthreads();
  }

  // ---- final (core_first): 8 waves x 8 p-tiles each, all frags prefetched --
  {
    half8 b0 = *(const half8*)&Vt[0][sl][quad * 8];
    half8 b0b = *(const half8*)&Vt[1][sl][quad * 8];
    half8 b1 = *(const half8*)&Vt[0][sl][32 + quad * 8];
    half8 b1b = *(const half8*)&Vt[1][sl][32 + quad * 8];
    b0 = b0 + b0b; b1 = b1 + b1b;
    half8 A[16];
#pragma unroll
    for (int j = 0; j < 8; ++j) {
      const _Float16* fp = ws + FIRST_OFF
                         + (size_t)(j * 8 + w) * 1024 + (size_t)lane * 8;
      A[2 * j]     = *(const half8*)fp;
      A[2 * j + 1] = *(const half8*)(fp + 512);
    }
    float f0 = 0.f, f1 = 0.f, f2 = 0.f, f3 = 0.f;
    const int fpar = w & 1, fbase = w >> 1;
#pragma unroll
    for (int j = 0; j < 8; ++j) {
      f32x4 dd = {0.f, 0.f, 0.f, 0.f};
      dd = __builtin_amdgcn_mfma_f32_16x16x32_f16(A[2 * j],     b0, dd, 0, 0, 0);
      dd = __builtin_amdgcn_mfma_f32_16x16x32_f16(A[2 * j + 1], b1, dd, 0, 0, 0);
      float xv = (float)XT[sl][fpar * 40 + 4 * j + fbase];   // x[s,0,p=8j+w]
      f0 += xv * dd[0]; f1 += xv * dd[1]; f2 += xv * dd[2]; f3 += xv * dd[3];
    }
    Red[w][quad * 4 + 0][sl] = f0;
    Red[w][quad * 4 + 1][sl] = f1;
    Red[w][quad * 4 + 2][sl] = f2;
    Red[w][quad * 4 + 3][sl] = f3;
  }
  __syncthreads();
  if (tid < 256) {
    int c = tid >> 4, s = tid & 15;
    if (c < 10) {
      float sum = 0.f;
#pragma unroll
      for (int ww = 0; ww < 8; ++ww) sum += Red[ww][c][s];
      out[((size_t)blk * 16 + s) * 10 + c] = sum;
    }
  }
}

extern "C" void kernel_launch(void* const* d_in, const int* in_sizes, int n_in,
                              void* d_out, int out_size, void* d_ws, size_t ws_size,
                              hipStream_t stream) {
  const float* x  = (const float*)d_in[0];   // (4096,8,64)
  const float* cf = (const float*)d_in[1];   // (10,64,64)
  const float* cm = (const float*)d_in[2];   // (6,64,64,64)
  const float* cl = (const float*)d_in[3];   // (64,64)
  _Float16* ws = (_Float16*)d_ws;            // ~3.3 MB used
  float* out = (float*)d_out;
  tt_swz<<<dim3((N_FRAGS * 64 + 255) / 256), dim3(256), 0, stream>>>(cf, cm, cl, ws);
  tt_main<<<dim3(256), dim3(512), 0, stream>>>(x, ws, out);
}

// Round 6
// 126.084 us; speedup vs baseline: 1.2659x; 1.2659x over previous
//
#include <hip/hip_runtime.h>

// Tensor-train forward, B=4096 N=8 F=64 D=64 C=10.
// R6 = R1 structure exactly (256x512, 16 samples/block, f32 Xs, 55.8 KB LDS ->
// 2 blocks/CU so co-resident blocks dedup the shared A-stream through L1),
// plus a batch-4 double-buffered A-prefetch (≈8 loads in flight/wave, rolled
// loop) to close the in-flight-depth gap toward the ~56 B/cyc/CU L2 share.
// R5 failed via launch_bounds(512,2) = 1 block/CU + over-batched loads; avoid.

typedef _Float16 half8 __attribute__((ext_vector_type(8)));
typedef _Float16 half4 __attribute__((ext_vector_type(4)));
typedef float f32x4 __attribute__((ext_vector_type(4)));

#define LAST_OFF   0          // 4 tiles * 2 kt * 64 lanes * 8 halves = 4096
#define MID_OFF    4096
#define MID_SZ     262144     // per mid core: 256 tiles * 2 * 64 * 8
#define FIRST_OFF  1576960    // 4096 + 6*262144
#define N_FRAGS    3208       // 8 (last) + 3072 (mid) + 128 (first)

// ---------- prologue: fp32 cores -> f16, MFMA-A-fragment swizzled ----------
// A-frag (16x16x32 f16): lane holds A[m=lane&15][k=(lane>>4)*8 + j], j=0..7.
__global__ __launch_bounds__(256) void tt_swz(
    const float* __restrict__ cf,   // core_first (10,64,64)  [c][p][r]
    const float* __restrict__ cm,   // cores_mid  (6,64,64,64)[ci][l][p][r]
    const float* __restrict__ cl,   // core_last  (64,64)     [l][p]
    _Float16* __restrict__ ws)
{
  int gid = blockIdx.x * 256 + threadIdx.x;
  if (gid >= N_FRAGS * 64) return;
  int lane = gid & 63, frag = gid >> 6;
  int quad = lane >> 4, m16 = lane & 15;
  half8 hv;
  _Float16* dst;
  if (frag < 8) {                       // core_last: rows l (4 tiles), k = p
    int t = frag >> 1, kt = frag & 1;
    int l = t * 16 + m16;
    const float* s = cl + l * 64 + kt * 32 + quad * 8;
#pragma unroll
    for (int j = 0; j < 8; ++j) hv[j] = (_Float16)s[j];
    dst = ws + LAST_OFF + (size_t)((t * 2 + kt) * 64 + lane) * 8;
  } else if (frag < 8 + 3072) {         // mid cores: rows (p,l), k = r
    int f2 = frag - 8;
    int ci = f2 >> 9, rem = f2 & 511;
    int t = rem >> 1, kt = rem & 1;
    int l = (t & 3) * 16 + m16, p = t >> 2;
    const float* s = cm + (((size_t)ci * 64 + l) * 64 + p) * 64 + kt * 32 + quad * 8;
#pragma unroll
    for (int j = 0; j < 8; ++j) hv[j] = (_Float16)s[j];
    dst = ws + MID_OFF + (size_t)ci * MID_SZ + (size_t)(rem * 64 + lane) * 8;
  } else {                              // core_first: rows c (pad 16), k = r
    int f2 = frag - 3080;
    int t = f2 >> 1, kt = f2 & 1;
    int c = m16, p = t;
    if (c < 10) {
      const float* s = cf + ((size_t)(c * 64 + p)) * 64 + kt * 32 + quad * 8;
#pragma unroll
      for (int j = 0; j < 8; ++j) hv[j] = (_Float16)s[j];
    } else {
#pragma unroll
      for (int j = 0; j < 8; ++j) hv[j] = (_Float16)0.f;
    }
    dst = ws + FIRST_OFF + (size_t)((t * 2 + kt) * 64 + lane) * 8;
  }
  *(half8*)dst = hv;
}

// batch-4 A prefetch: 4 tiles (8 dwordx4 loads) per batch
#define LD4(DST, JB) { _Pragma("unroll") for (int i_ = 0; i_ < 4; ++i_) { \
    const _Float16* fp_ = wl + (size_t)((JB) + i_) * 8192; \
    DST[2*i_]   = *(const half8*)fp_; \
    DST[2*i_+1] = *(const half8*)(fp_ + 512); } }

#define CP4(SRC, JB) { _Pragma("unroll") for (int i_ = 0; i_ < 4; ++i_) { \
    f32x4 dd_ = {0.f, 0.f, 0.f, 0.f}; \
    dd_ = __builtin_amdgcn_mfma_f32_16x16x32_f16(SRC[2*i_],   b0, dd_, 0, 0, 0); \
    dd_ = __builtin_amdgcn_mfma_f32_16x16x32_f16(SRC[2*i_+1], b1, dd_, 0, 0, 0); \
    float xv_ = Xs[(xrow + 2 * ((JB) + i_) + pq) * 17 + sl]; \
    a0 += xv_ * dd_[0]; a1 += xv_ * dd_[1]; \
    a2 += xv_ * dd_[2]; a3 += xv_ * dd_[3]; } }

// ------------------- main chain: 256 blocks x 512 threads ------------------
__global__ __launch_bounds__(512) void tt_main(
    const float* __restrict__ x,        // (4096, 8, 64)
    const _Float16* __restrict__ ws,
    float* __restrict__ out)            // (4096, 10)
{
  __shared__ __align__(16) float Xs[512 * 17];          // [n*64+p][s], padded
  __shared__ __align__(16) _Float16 Vt[2][16][72];      // [part][s][l], padded
  __shared__ __align__(16) float Red[8][16][16];        // [wave][c][s]
  const int tid = threadIdx.x;
  const int w = tid >> 6, lane = tid & 63;
  const int quad = lane >> 4, sl = lane & 15;
  const int blk = blockIdx.x;

  // ---- stage x for the block's 16 samples, transposed to [n*64+p][s] ----
  {
    const float* xb = x + (size_t)blk * 16 * 512;
    int s = tid & 15, b0 = (tid >> 4) * 4;
#pragma unroll
    for (int k = 0; k < 4; ++k) {
      int base = b0 + k * 128;                       // n*64+p
      float4 v = *(const float4*)(xb + s * 512 + base);
      Xs[(base + 0) * 17 + s] = v.x;
      Xs[(base + 1) * 17 + s] = v.y;
      Xs[(base + 2) * 17 + s] = v.z;
      Xs[(base + 3) * 17 + s] = v.w;
    }
  }
  __syncthreads();

  // ---- GEMM1: v7[l,s] = sum_p core_last[l,p] x[s,7,p]; K split over waves
  {
    int kt = w >> 2, tt = w & 3;
    half8 b;
#pragma unroll
    for (int j = 0; j < 8; ++j)
      b[j] = (_Float16)Xs[(448 + kt * 32 + quad * 8 + j) * 17 + sl];
    half8 a = *(const half8*)(ws + LAST_OFF + (size_t)((tt * 2 + kt) * 64 + lane) * 8);
    f32x4 d = {0.f, 0.f, 0.f, 0.f};
    d = __builtin_amdgcn_mfma_f32_16x16x32_f16(a, b, d, 0, 0, 0);
    half4 hv;
#pragma unroll
    for (int r = 0; r < 4; ++r) hv[r] = (_Float16)d[r];
    *(half4*)&Vt[kt][sl][tt * 16 + quad * 4] = hv;    // partial half kt
  }
  __syncthreads();

  const int h = w >> 2, g = w & 3;
  const int pq = w >> 2;                 // p = 2j + pq for tile t = 8j + w
  // ---- 6 middle steps (right-to-left: cores_mid[5] .. cores_mid[0]) ----
  for (int step = 0; step < 6; ++step) {
    int ci = 5 - step;
    const _Float16* base = ws + MID_OFF + (size_t)ci * MID_SZ;
    // B-frags: v[r][s], summing the two partial halves
    half8 b0 = *(const half8*)&Vt[0][sl][quad * 8];
    half8 b0p = *(const half8*)&Vt[1][sl][quad * 8];
    half8 b1 = *(const half8*)&Vt[0][sl][32 + quad * 8];
    half8 b1p = *(const half8*)&Vt[1][sl][32 + quad * 8];
    b0 = b0 + b0p; b1 = b1 + b1p;
    __syncthreads();                                  // reads done before overwrite
    float a0 = 0.f, a1 = 0.f, a2 = 0.f, a3 = 0.f;
    const int xrow = (ci + 1) * 64;
    const _Float16* wl = base + (size_t)w * 1024 + (size_t)lane * 8;
    half8 Ba[8], Bb[8];
    LD4(Ba, 0);
    LD4(Bb, 4);
    for (int jb = 0; jb < 3; ++jb) {                  // rolled: steady state
      int j0 = jb * 8;
      CP4(Ba, j0);
      LD4(Ba, j0 + 8);
      CP4(Bb, j0 + 4);
      LD4(Bb, j0 + 12);
    }
    CP4(Ba, 24);
    CP4(Bb, 28);
    half4 hv;
    hv[0] = (_Float16)a0; hv[1] = (_Float16)a1;
    hv[2] = (_Float16)a2; hv[3] = (_Float16)a3;
    *(half4*)&Vt[h][sl][g * 16 + quad * 4] = hv;      // partial half h (p-split)
    __syncthreads();
  }

  // ---- final: out[c,s] = sum_{p,r} core_first[c,p,r] x[s,0,p] v[r] ----
  {
    half8 b0 = *(const half8*)&Vt[0][sl][quad * 8];
    half8 b0p = *(const half8*)&Vt[1][sl][quad * 8];
    half8 b1 = *(const half8*)&Vt[0][sl][32 + quad * 8];
    half8 b1p = *(const half8*)&Vt[1][sl][32 + quad * 8];
    b0 = b0 + b0p; b1 = b1 + b1p;
    float f0 = 0.f, f1 = 0.f, f2 = 0.f, f3 = 0.f;
#pragma unroll
    for (int j = 0; j < 8; ++j) {
      int t = 8 * j + w;                              // tile t = p
      const _Float16* fp = ws + FIRST_OFF + (size_t)t * 1024 + (size_t)lane * 8;
      half8 A0 = *(const half8*)fp;
      half8 A1 = *(const half8*)(fp + 512);
      f32x4 dd = {0.f, 0.f, 0.f, 0.f};
      dd = __builtin_amdgcn_mfma_f32_16x16x32_f16(A0, b0, dd, 0, 0, 0);
      dd = __builtin_amdgcn_mfma_f32_16x16x32_f16(A1, b1, dd, 0, 0, 0);
      float xv = Xs[t * 17 + sl];                     // x[s, 0, p]
      f0 += xv * dd[0]; f1 += xv * dd[1];
      f2 += xv * dd[2]; f3 += xv * dd[3];
    }
    Red[w][quad * 4 + 0][sl] = f0;
    Red[w][quad * 4 + 1][sl] = f1;
    Red[w][quad * 4 + 2][sl] = f2;
    Red[w][quad * 4 + 3][sl] = f3;
  }
  __syncthreads();
  if (tid < 256) {
    int c = tid >> 4, s = tid & 15;
    float sum = 0.f;
#pragma unroll
    for (int ww = 0; ww < 8; ++ww) sum += Red[ww][c][s];
    if (c < 10) out[((size_t)blk * 16 + s) * 10 + c] = sum;
  }
}

extern "C" void kernel_launch(void* const* d_in, const int* in_sizes, int n_in,
                              void* d_out, int out_size, void* d_ws, size_t ws_size,
                              hipStream_t stream) {
  const float* x  = (const float*)d_in[0];   // (4096,8,64)
  const float* cf = (const float*)d_in[1];   // (10,64,64)
  const float* cm = (const float*)d_in[2];   // (6,64,64,64)
  const float* cl = (const float*)d_in[3];   // (64,64)
  _Float16* ws = (_Float16*)d_ws;            // ~3.3 MB used
  float* out = (float*)d_out;
  tt_swz<<<dim3((N_FRAGS * 64 + 255) / 256), dim3(256), 0, stream>>>(cf, cm, cl, ws);
  tt_main<<<dim3(256), dim3(512), 0, stream>>>(x, ws, out);
}

// Round 7
// 107.656 us; speedup vs baseline: 1.4826x; 1.1712x over previous
//
#include <hip/hip_runtime.h>

// Tensor-train forward, B=4096 N=8 F=64 D=64 C=10.
// R7 = R1 structure exactly (the fastest variant; all explicit-prefetch
// variants R4/R5/R6 regressed -> compiler schedules better), scaled from
// 8 -> 16 waves per CU (256 blocks x 1024 threads, still 1 block/CU so the
// per-CU A-stream stays 3.15 MB). Pure TLP play against the ~230-cyc
// per-load latency wall diagnosed from R1 (depth~2/wave, 33 B/cyc/CU).

typedef _Float16 half8 __attribute__((ext_vector_type(8)));
typedef _Float16 half4 __attribute__((ext_vector_type(4)));
typedef float f32x4 __attribute__((ext_vector_type(4)));

#define LAST_OFF   0          // 4 tiles * 2 kt * 64 lanes * 8 halves = 4096
#define MID_OFF    4096
#define MID_SZ     262144     // per mid core: 256 tiles * 2 * 64 * 8
#define FIRST_OFF  1576960    // 4096 + 6*262144
#define N_FRAGS    3208       // 8 (last) + 3072 (mid) + 128 (first)

// ---------- prologue: fp32 cores -> f16, MFMA-A-fragment swizzled ----------
// A-frag (16x16x32 f16): lane holds A[m=lane&15][k=(lane>>4)*8 + j], j=0..7.
__global__ __launch_bounds__(256) void tt_swz(
    const float* __restrict__ cf,   // core_first (10,64,64)  [c][p][r]
    const float* __restrict__ cm,   // cores_mid  (6,64,64,64)[ci][l][p][r]
    const float* __restrict__ cl,   // core_last  (64,64)     [l][p]
    _Float16* __restrict__ ws)
{
  int gid = blockIdx.x * 256 + threadIdx.x;
  if (gid >= N_FRAGS * 64) return;
  int lane = gid & 63, frag = gid >> 6;
  int quad = lane >> 4, m16 = lane & 15;
  half8 hv;
  _Float16* dst;
  if (frag < 8) {                       // core_last: rows l (4 tiles), k = p
    int t = frag >> 1, kt = frag & 1;
    int l = t * 16 + m16;
    const float* s = cl + l * 64 + kt * 32 + quad * 8;
#pragma unroll
    for (int j = 0; j < 8; ++j) hv[j] = (_Float16)s[j];
    dst = ws + LAST_OFF + (size_t)((t * 2 + kt) * 64 + lane) * 8;
  } else if (frag < 8 + 3072) {         // mid cores: rows (p,l), k = r
    int f2 = frag - 8;
    int ci = f2 >> 9, rem = f2 & 511;
    int t = rem >> 1, kt = rem & 1;
    int l = (t & 3) * 16 + m16, p = t >> 2;
    const float* s = cm + (((size_t)ci * 64 + l) * 64 + p) * 64 + kt * 32 + quad * 8;
#pragma unroll
    for (int j = 0; j < 8; ++j) hv[j] = (_Float16)s[j];
    dst = ws + MID_OFF + (size_t)ci * MID_SZ + (size_t)(rem * 64 + lane) * 8;
  } else {                              // core_first: rows c (pad 16), k = r
    int f2 = frag - 3080;
    int t = f2 >> 1, kt = f2 & 1;
    int c = m16, p = t;
    if (c < 10) {
      const float* s = cf + ((size_t)(c * 64 + p)) * 64 + kt * 32 + quad * 8;
#pragma unroll
      for (int j = 0; j < 8; ++j) hv[j] = (_Float16)s[j];
    } else {
#pragma unroll
      for (int j = 0; j < 8; ++j) hv[j] = (_Float16)0.f;
    }
    dst = ws + FIRST_OFF + (size_t)((t * 2 + kt) * 64 + lane) * 8;
  }
  *(half8*)dst = hv;
}

// ------------------- main chain: 256 blocks x 1024 threads -----------------
__global__ __launch_bounds__(1024) void tt_main(
    const float* __restrict__ x,        // (4096, 8, 64)
    const _Float16* __restrict__ ws,
    float* __restrict__ out)            // (4096, 10)
{
  __shared__ __align__(16) float Xs[512 * 17];          // [n*64+p][s], padded
  __shared__ __align__(16) _Float16 Vt[4][16][72];      // [part][s][l], padded
  __shared__ __align__(16) float Red[16][16][16];       // [wave][c][s]
  const int tid = threadIdx.x;
  const int w = tid >> 6, lane = tid & 63;
  const int quad = lane >> 4, sl = lane & 15;
  const int blk = blockIdx.x;

  // ---- stage x for the block's 16 samples, transposed to [n*64+p][s] ----
  {
    const float* xb = x + (size_t)blk * 16 * 512;
    int s = tid & 15, b0 = (tid >> 4) * 4;
#pragma unroll
    for (int k = 0; k < 2; ++k) {
      int base = b0 + k * 256;                       // n*64+p
      float4 v = *(const float4*)(xb + s * 512 + base);
      Xs[(base + 0) * 17 + s] = v.x;
      Xs[(base + 1) * 17 + s] = v.y;
      Xs[(base + 2) * 17 + s] = v.z;
      Xs[(base + 3) * 17 + s] = v.w;
    }
    // zero the two spare Vt partials (only waves' classes 2,3 write them later)
    _Float16* vz = &Vt[2][0][0];
    for (int idx = tid; idx < 2 * 16 * 72; idx += 1024) vz[idx] = (_Float16)0.f;
  }
  __syncthreads();

  // ---- GEMM1: v7[l,s] = sum_p core_last[l,p] x[s,7,p]; 8 wave-tasks ----
  if (w < 8) {
    int kt = w >> 2, tt = w & 3;
    half8 b;
#pragma unroll
    for (int j = 0; j < 8; ++j)
      b[j] = (_Float16)Xs[(448 + kt * 32 + quad * 8 + j) * 17 + sl];
    half8 a = *(const half8*)(ws + LAST_OFF + (size_t)((tt * 2 + kt) * 64 + lane) * 8);
    f32x4 d = {0.f, 0.f, 0.f, 0.f};
    d = __builtin_amdgcn_mfma_f32_16x16x32_f16(a, b, d, 0, 0, 0);
    half4 hv;
#pragma unroll
    for (int r = 0; r < 4; ++r) hv[r] = (_Float16)d[r];
    *(half4*)&Vt[kt][sl][tt * 16 + quad * 4] = hv;    // partial half kt
  }
  __syncthreads();

  const int pq = w >> 2;                 // p-class: p = 4j + pq (also partial id)
  const int lch = (w & 3) * 16;          // l-chunk
  // ---- 6 middle steps (right-to-left: cores_mid[5] .. cores_mid[0]) ----
  for (int step = 0; step < 6; ++step) {
    int ci = 5 - step;
    const _Float16* base = ws + MID_OFF + (size_t)ci * MID_SZ;
    // B-frags: v[r][s] = sum of 4 partials
    half8 b0 = *(const half8*)&Vt[0][sl][quad * 8];
    half8 b0b = *(const half8*)&Vt[1][sl][quad * 8];
    half8 b0c = *(const half8*)&Vt[2][sl][quad * 8];
    half8 b0d = *(const half8*)&Vt[3][sl][quad * 8];
    half8 b1 = *(const half8*)&Vt[0][sl][32 + quad * 8];
    half8 b1b = *(const half8*)&Vt[1][sl][32 + quad * 8];
    half8 b1c = *(const half8*)&Vt[2][sl][32 + quad * 8];
    half8 b1d = *(const half8*)&Vt[3][sl][32 + quad * 8];
    b0 = (b0 + b0b) + (b0c + b0d);
    b1 = (b1 + b1b) + (b1c + b1d);
    __syncthreads();                                  // reads done before overwrite
    float a0 = 0.f, a1 = 0.f, a2 = 0.f, a3 = 0.f;
    const int xrow = (ci + 1) * 64;
#pragma unroll
    for (int j = 0; j < 16; ++j) {
      int t = 16 * j + w;                             // tile: p = 4j+pq, lch = w&3
      const _Float16* fp = base + (size_t)t * 1024 + (size_t)lane * 8;
      half8 A0 = *(const half8*)fp;
      half8 A1 = *(const half8*)(fp + 512);
      f32x4 dd = {0.f, 0.f, 0.f, 0.f};
      dd = __builtin_amdgcn_mfma_f32_16x16x32_f16(A0, b0, dd, 0, 0, 0);
      dd = __builtin_amdgcn_mfma_f32_16x16x32_f16(A1, b1, dd, 0, 0, 0);
      float xv = Xs[(xrow + 4 * j + pq) * 17 + sl];   // x[s, ci+1, p]
      a0 += xv * dd[0]; a1 += xv * dd[1];
      a2 += xv * dd[2]; a3 += xv * dd[3];
    }
    half4 hv;
    hv[0] = (_Float16)a0; hv[1] = (_Float16)a1;
    hv[2] = (_Float16)a2; hv[3] = (_Float16)a3;
    *(half4*)&Vt[pq][sl][lch + quad * 4] = hv;        // partial class pq
    __syncthreads();
  }

  // ---- final: out[c,s] = sum_{p,r} core_first[c,p,r] x[s,0,p] v[r] ----
  {
    half8 b0 = *(const half8*)&Vt[0][sl][quad * 8];
    half8 b0b = *(const half8*)&Vt[1][sl][quad * 8];
    half8 b0c = *(const half8*)&Vt[2][sl][quad * 8];
    half8 b0d = *(const half8*)&Vt[3][sl][quad * 8];
    half8 b1 = *(const half8*)&Vt[0][sl][32 + quad * 8];
    half8 b1b = *(const half8*)&Vt[1][sl][32 + quad * 8];
    half8 b1c = *(const half8*)&Vt[2][sl][32 + quad * 8];
    half8 b1d = *(const half8*)&Vt[3][sl][32 + quad * 8];
    b0 = (b0 + b0b) + (b0c + b0d);
    b1 = (b1 + b1b) + (b1c + b1d);
    float f0 = 0.f, f1 = 0.f, f2 = 0.f, f3 = 0.f;
#pragma unroll
    for (int j = 0; j < 4; ++j) {
      int t = 16 * j + w;                             // tile t = p
      const _Float16* fp = ws + FIRST_OFF + (size_t)t * 1024 + (size_t)lane * 8;
      half8 A0 = *(const half8*)fp;
      half8 A1 = *(const half8*)(fp + 512);
      f32x4 dd = {0.f, 0.f, 0.f, 0.f};
      dd = __builtin_amdgcn_mfma_f32_16x16x32_f16(A0, b0, dd, 0, 0, 0);
      dd = __builtin_amdgcn_mfma_f32_16x16x32_f16(A1, b1, dd, 0, 0, 0);
      float xv = Xs[t * 17 + sl];                     // x[s, 0, p]
      f0 += xv * dd[0]; f1 += xv * dd[1];
      f2 += xv * dd[2]; f3 += xv * dd[3];
    }
    Red[w][quad * 4 + 0][sl] = f0;
    Red[w][quad * 4 + 1][sl] = f1;
    Red[w][quad * 4 + 2][sl] = f2;
    Red[w][quad * 4 + 3][sl] = f3;
  }
  __syncthreads();
  if (tid < 256) {
    int c = tid >> 4, s = tid & 15;
    if (c < 10) {
      float sum = 0.f;
#pragma unroll
      for (int ww = 0; ww < 16; ++ww) sum += Red[ww][c][s];
      out[((size_t)blk * 16 + s) * 10 + c] = sum;
    }
  }
}

extern "C" void kernel_launch(void* const* d_in, const int* in_sizes, int n_in,
                              void* d_out, int out_size, void* d_ws, size_t ws_size,
                              hipStream_t stream) {
  const float* x  = (const float*)d_in[0];   // (4096,8,64)
  const float* cf = (const float*)d_in[1];   // (10,64,64)
  const float* cm = (const float*)d_in[2];   // (6,64,64,64)
  const float* cl = (const float*)d_in[3];   // (64,64)
  _Float16* ws = (_Float16*)d_ws;            // ~3.3 MB used
  float* out = (float*)d_out;
  tt_swz<<<dim3((N_FRAGS * 64 + 255) / 256), dim3(256), 0, stream>>>(cf, cm, cl, ws);
  tt_main<<<dim3(256), dim3(1024), 0, stream>>>(x, ws, out);
}